// Round 1
// baseline (2863.952 us; speedup 1.0000x reference)
//
#include <hip/hip_runtime.h>
#include <math.h>

#define HDIM 1024
#define NHEADS 16
#define HEADD 64
#define SEQLEN 2048
#define NBATCH 2
#define NROWS (NBATCH*SEQLEN)

union F4 { float4 v; float f[4]; };

// swizzled float-offset for a [64][64] f32 tile stored flat: quad rotated by row/4
__device__ __forceinline__ int swz4(int row, int quad) {
    return row*64 + (((quad) + ((row)>>2)) & 15)*4;
}

// ---------------- LayerNorm: one block per row ----------------
__global__ __launch_bounds__(256) void ln_kernel(
        const float* __restrict__ x, const float* __restrict__ w,
        const float* __restrict__ b, float* __restrict__ xn) {
    int row = blockIdx.x;
    F4 vv; vv.v = ((const float4*)(x + (size_t)row*HDIM))[threadIdx.x];
    float s  = vv.f[0]+vv.f[1]+vv.f[2]+vv.f[3];
    float ss = vv.f[0]*vv.f[0]+vv.f[1]*vv.f[1]+vv.f[2]*vv.f[2]+vv.f[3]*vv.f[3];
    #pragma unroll
    for (int off = 32; off > 0; off >>= 1) {
        s  += __shfl_xor(s, off);
        ss += __shfl_xor(ss, off);
    }
    __shared__ float red[8];
    int wid = threadIdx.x >> 6;
    if ((threadIdx.x & 63) == 0) { red[wid] = s; red[wid+4] = ss; }
    __syncthreads();
    s  = red[0]+red[1]+red[2]+red[3];
    ss = red[4]+red[5]+red[6]+red[7];
    float mean = s * (1.0f/HDIM);
    float var  = ss * (1.0f/HDIM) - mean*mean;
    float rstd = rsqrtf(var + 1e-5f);
    F4 wv; wv.v = ((const float4*)w)[threadIdx.x];
    F4 bv; bv.v = ((const float4*)b)[threadIdx.x];
    F4 o;
    #pragma unroll
    for (int j = 0; j < 4; ++j)
        o.f[j] = (vv.f[j]-mean)*rstd*wv.f[j] + bv.f[j];
    ((float4*)(xn + (size_t)row*HDIM))[threadIdx.x] = o.v;
}

// ---------------- fp32 tiled GEMM: C = A @ W (+bias) ----------------
// MODE 0: write head-major [B][NH][S][HD] with bias (QKV projections)
// MODE 1: write row-major out = acc + bias + residual (output projection)
template<int MODE>
__global__ __launch_bounds__(256) void gemm_kernel(
        const float* __restrict__ A, const float* __restrict__ W,
        const float* __restrict__ bias, const float* __restrict__ residual,
        float* __restrict__ out) {
    __shared__ float As[16*64];   // As[kk][m]
    __shared__ float Bs[16*64];   // Bs[kk][n]
    int row0 = blockIdx.x * 64;
    int col0 = blockIdx.y * 64;
    int t = threadIdx.x;
    int tx = t & 15, ty = t >> 4;
    int ar = t >> 2, akq = t & 3;   // A staging: row, k-quad
    int bk = t >> 4, bq = t & 15;   // B staging: k-row, n-quad
    float acc[4][4] = {};
    for (int k0 = 0; k0 < HDIM; k0 += 16) {
        F4 av, bvv;
        av.v  = *(const float4*)(A + (size_t)(row0+ar)*HDIM + k0 + akq*4);
        bvv.v = *(const float4*)(W + (size_t)(k0+bk)*HDIM + col0 + bq*4);
        __syncthreads();
        #pragma unroll
        for (int j = 0; j < 4; ++j) As[(akq*4+j)*64 + ar] = av.f[j];
        *(float4*)(Bs + bk*64 + bq*4) = bvv.v;
        __syncthreads();
        #pragma unroll
        for (int kk = 0; kk < 16; ++kk) {
            F4 a, b;
            a.v = *(const float4*)(As + kk*64 + ty*4);
            b.v = *(const float4*)(Bs + kk*64 + tx*4);
            #pragma unroll
            for (int i = 0; i < 4; ++i)
                #pragma unroll
                for (int j = 0; j < 4; ++j)
                    acc[i][j] += a.f[i]*b.f[j];
        }
    }
    #pragma unroll
    for (int i = 0; i < 4; ++i) {
        int r = row0 + ty*4 + i;
        int bb = r >> 11, sq = r & (SEQLEN-1);
        #pragma unroll
        for (int j = 0; j < 4; ++j) {
            int c = col0 + tx*4 + j;
            float val = acc[i][j] + bias[c];
            if (MODE == 0) {
                int h = c >> 6, d = c & 63;
                out[(((size_t)(bb*NHEADS + h))*SEQLEN + sq)*HEADD + d] = val;
            } else {
                out[(size_t)r*HDIM + c] = val + residual[(size_t)r*HDIM + c];
            }
        }
    }
}

// ---------------- L2 normalize rows of 64 (one wave per row) ----------------
__global__ __launch_bounds__(256) void l2norm_kernel(float* __restrict__ p) {
    size_t row = (size_t)blockIdx.x*4 + (threadIdx.x >> 6);
    int lane = threadIdx.x & 63;
    float val = p[row*64 + lane];
    float ss = val*val;
    #pragma unroll
    for (int off = 32; off > 0; off >>= 1) ss += __shfl_xor(ss, off);
    float n = sqrtf(ss);
    float sc = 1.0f / fmaxf(n, 1e-12f);
    p[row*64 + lane] = val * sc;
}

// ---------------- flash-style attention step ----------------
// stin/k/v head-major [B*NH][S][HD]; out head-major (ROWMAJOR_OUT=0) or [B][S][H] (=1)
template<int ROWMAJOR_OUT>
__global__ __launch_bounds__(256) void attn_kernel(
        const float* __restrict__ stin, const float* __restrict__ kin,
        const float* __restrict__ vin, float* __restrict__ out) {
    __shared__ float Qs[64*64];   // swizzled
    __shared__ float Ks[64*64];   // swizzled
    __shared__ float Vs[64*64];   // linear
    __shared__ float Ps[64*64];   // swizzled
    int bh = blockIdx.y;
    int q0 = blockIdx.x * 64;
    const float* Qb = stin + ((size_t)bh*SEQLEN + q0)*HEADD;
    const float* Kb = kin + (size_t)bh*SEQLEN*HEADD;
    const float* Vb = vin + (size_t)bh*SEQLEN*HEADD;
    int t = threadIdx.x;
    int tx = t & 15, ty = t >> 4;
    #pragma unroll
    for (int ii = 0; ii < 4; ++ii) {
        int fi = t + 256*ii;
        int r = fi >> 4, qd = fi & 15;
        *(float4*)(Qs + swz4(r, qd)) = *(const float4*)(Qb + r*64 + qd*4);
    }
    float acc[4][4] = {};
    float mrow[4] = {-1e30f,-1e30f,-1e30f,-1e30f};
    float lrow[4] = {0.f,0.f,0.f,0.f};
    for (int kt = 0; kt < SEQLEN/64; ++kt) {
        __syncthreads();   // protect previous iteration's LDS reads
        const float* Kt = Kb + kt*64*64;
        const float* Vt = Vb + kt*64*64;
        #pragma unroll
        for (int ii = 0; ii < 4; ++ii) {
            int fi = t + 256*ii;
            int r = fi >> 4, qd = fi & 15;
            *(float4*)(Ks + swz4(r, qd)) = *(const float4*)(Kt + r*64 + qd*4);
            *(float4*)(Vs + r*64 + qd*4) = *(const float4*)(Vt + r*64 + qd*4);
        }
        __syncthreads();
        // sim[m][n] = q_m . k_n ; rows m=ty*4+i, key cols n=tx*4+j
        float sim[4][4] = {};
        #pragma unroll
        for (int d4 = 0; d4 < 16; ++d4) {
            F4 qa[4], kb[4];
            #pragma unroll
            for (int i = 0; i < 4; ++i) qa[i].v = *(const float4*)(Qs + swz4(ty*4+i, d4));
            #pragma unroll
            for (int j = 0; j < 4; ++j) kb[j].v = *(const float4*)(Ks + swz4(tx*4+j, d4));
            #pragma unroll
            for (int i = 0; i < 4; ++i)
                #pragma unroll
                for (int j = 0; j < 4; ++j)
                    sim[i][j] += qa[i].f[0]*kb[j].f[0] + qa[i].f[1]*kb[j].f[1]
                               + qa[i].f[2]*kb[j].f[2] + qa[i].f[3]*kb[j].f[3];
        }
        // online softmax over this tile
        #pragma unroll
        for (int i = 0; i < 4; ++i) {
            float tm = fmaxf(fmaxf(sim[i][0], sim[i][1]), fmaxf(sim[i][2], sim[i][3]));
            #pragma unroll
            for (int off = 8; off > 0; off >>= 1) tm = fmaxf(tm, __shfl_xor(tm, off));
            float nm = fmaxf(mrow[i], tm);
            float sc = __expf(mrow[i] - nm);
            mrow[i] = nm;
            float rs = 0.f;
            F4 pw;
            #pragma unroll
            for (int j = 0; j < 4; ++j) {
                pw.f[j] = __expf(sim[i][j] - nm);
                rs += pw.f[j];
            }
            #pragma unroll
            for (int off = 8; off > 0; off >>= 1) rs += __shfl_xor(rs, off);
            lrow[i] = lrow[i]*sc + rs;
            #pragma unroll
            for (int j = 0; j < 4; ++j) acc[i][j] *= sc;
            *(float4*)(Ps + swz4(ty*4+i, tx)) = pw.v;
        }
        __syncthreads();
        // acc[m][d] += P[m][:] @ V[:][d], dims d = tx*4+j
        #pragma unroll
        for (int n4 = 0; n4 < 16; ++n4) {
            F4 pr[4], vr[4];
            #pragma unroll
            for (int i = 0; i < 4; ++i) pr[i].v = *(const float4*)(Ps + swz4(ty*4+i, n4));
            #pragma unroll
            for (int nn = 0; nn < 4; ++nn) vr[nn].v = *(const float4*)(Vs + (n4*4+nn)*64 + tx*4);
            #pragma unroll
            for (int i = 0; i < 4; ++i)
                #pragma unroll
                for (int j = 0; j < 4; ++j)
                    acc[i][j] += pr[i].f[0]*vr[0].f[j] + pr[i].f[1]*vr[1].f[j]
                               + pr[i].f[2]*vr[2].f[j] + pr[i].f[3]*vr[3].f[j];
        }
    }
    #pragma unroll
    for (int i = 0; i < 4; ++i) {
        float inv = 1.0f / lrow[i];
        int srow = q0 + ty*4 + i;
        F4 o;
        #pragma unroll
        for (int j = 0; j < 4; ++j) o.f[j] = acc[i][j]*inv;
        if (ROWMAJOR_OUT) {
            int bb = bh / NHEADS, h = bh % NHEADS;
            *(float4*)(out + ((size_t)bb*SEQLEN + srow)*HDIM + h*HEADD + tx*4) = o.v;
        } else {
            *(float4*)(out + ((size_t)bh*SEQLEN + srow)*HEADD + tx*4) = o.v;
        }
    }
}

extern "C" void kernel_launch(void* const* d_in, const int* in_sizes, int n_in,
                              void* d_out, int out_size, void* d_ws, size_t ws_size,
                              hipStream_t stream) {
    const float* hs = (const float*)d_in[0];
    const float* Wq = (const float*)d_in[1];
    const float* bq = (const float*)d_in[2];
    const float* Wk = (const float*)d_in[3];
    const float* bk = (const float*)d_in[4];
    const float* Wv = (const float*)d_in[5];
    const float* bv = (const float*)d_in[6];
    const float* Wo = (const float*)d_in[7];
    const float* bo = (const float*)d_in[8];
    const float* lw = (const float*)d_in[9];
    const float* lb = (const float*)d_in[10];
    float* out = (float*)d_out;
    float* ws = (float*)d_ws;
    const size_t NE = (size_t)NROWS * HDIM;   // 4.19M floats per buffer
    float* xn = ws;            // post-LN activations (reused as s2 later)
    float* q  = ws + NE;       // head-major
    float* k  = ws + 2*NE;
    float* v  = ws + 3*NE;
    float* s1 = ws + 4*NE;
    float* s2 = xn;            // xn dead after projections

    ln_kernel<<<NROWS, 256, 0, stream>>>(hs, lw, lb, xn);
    dim3 gg(NROWS/64, HDIM/64);
    gemm_kernel<0><<<gg, 256, 0, stream>>>(xn, Wq, bq, nullptr, q);
    gemm_kernel<0><<<gg, 256, 0, stream>>>(xn, Wk, bk, nullptr, k);
    gemm_kernel<0><<<gg, 256, 0, stream>>>(xn, Wv, bv, nullptr, v);
    int nrows64 = NROWS * NHEADS;  // 65536 rows of 64
    l2norm_kernel<<<nrows64/4, 256, 0, stream>>>(q);
    l2norm_kernel<<<nrows64/4, 256, 0, stream>>>(k);
    dim3 ag(SEQLEN/64, NBATCH*NHEADS);
    attn_kernel<0><<<ag, 256, 0, stream>>>(q, k, v, s1);
    attn_kernel<1><<<ag, 256, 0, stream>>>(s1, k, v, s2);
    gemm_kernel<1><<<gg, 256, 0, stream>>>(s2, Wo, bo, hs, out);
}

// Round 2
// 701.721 us; speedup vs baseline: 4.0813x; 4.0813x over previous
//
#include <hip/hip_runtime.h>
#include <hip/hip_bf16.h>
#include <math.h>

#define HDIM 1024
#define NHEADS 16
#define HEADD 64
#define SEQLEN 2048
#define NBATCH 2
#define NROWS (NBATCH*SEQLEN)
#define NBH (NBATCH*NHEADS)

typedef float f32x4 __attribute__((ext_vector_type(4)));
typedef short short8 __attribute__((ext_vector_type(8)));
typedef unsigned short us4v __attribute__((ext_vector_type(4)));

union F4 { float4 v; float f[4]; };

static __device__ __forceinline__ unsigned short f2bf(float x) {
    __hip_bfloat16 h = __float2bfloat16(x);
    return *(unsigned short*)&h;
}

// ---------------- LayerNorm: one block per row ----------------
__global__ __launch_bounds__(256) void ln_kernel(
        const float* __restrict__ x, const float* __restrict__ w,
        const float* __restrict__ b, float* __restrict__ xn) {
    int row = blockIdx.x;
    F4 vv; vv.v = ((const float4*)(x + (size_t)row*HDIM))[threadIdx.x];
    float s  = vv.f[0]+vv.f[1]+vv.f[2]+vv.f[3];
    float ss = vv.f[0]*vv.f[0]+vv.f[1]*vv.f[1]+vv.f[2]*vv.f[2]+vv.f[3]*vv.f[3];
    #pragma unroll
    for (int off = 32; off > 0; off >>= 1) {
        s  += __shfl_xor(s, off);
        ss += __shfl_xor(ss, off);
    }
    __shared__ float red[8];
    int wid = threadIdx.x >> 6;
    if ((threadIdx.x & 63) == 0) { red[wid] = s; red[wid+4] = ss; }
    __syncthreads();
    s  = red[0]+red[1]+red[2]+red[3];
    ss = red[4]+red[5]+red[6]+red[7];
    float mean = s * (1.0f/HDIM);
    float var  = ss * (1.0f/HDIM) - mean*mean;
    float rstd = rsqrtf(var + 1e-5f);
    F4 wv; wv.v = ((const float4*)w)[threadIdx.x];
    F4 bv; bv.v = ((const float4*)b)[threadIdx.x];
    F4 o;
    #pragma unroll
    for (int j = 0; j < 4; ++j)
        o.f[j] = (vv.f[j]-mean)*rstd*wv.f[j] + bv.f[j];
    ((float4*)(xn + (size_t)row*HDIM))[threadIdx.x] = o.v;
}

// ---------------- fp32 tiled GEMM: C = A @ W (+bias) ----------------
template<int MODE>
__global__ __launch_bounds__(256) void gemm_kernel(
        const float* __restrict__ A, const float* __restrict__ W,
        const float* __restrict__ bias, const float* __restrict__ residual,
        float* __restrict__ out) {
    __shared__ float As[16*64];
    __shared__ float Bs[16*64];
    int row0 = blockIdx.x * 64;
    int col0 = blockIdx.y * 64;
    int t = threadIdx.x;
    int tx = t & 15, ty = t >> 4;
    int ar = t >> 2, akq = t & 3;
    int bk = t >> 4, bq = t & 15;
    float acc[4][4] = {};
    for (int k0 = 0; k0 < HDIM; k0 += 16) {
        F4 av, bvv;
        av.v  = *(const float4*)(A + (size_t)(row0+ar)*HDIM + k0 + akq*4);
        bvv.v = *(const float4*)(W + (size_t)(k0+bk)*HDIM + col0 + bq*4);
        __syncthreads();
        #pragma unroll
        for (int j = 0; j < 4; ++j) As[(akq*4+j)*64 + ar] = av.f[j];
        *(float4*)(Bs + bk*64 + bq*4) = bvv.v;
        __syncthreads();
        #pragma unroll
        for (int kk = 0; kk < 16; ++kk) {
            F4 a, b;
            a.v = *(const float4*)(As + kk*64 + ty*4);
            b.v = *(const float4*)(Bs + kk*64 + tx*4);
            #pragma unroll
            for (int i = 0; i < 4; ++i)
                #pragma unroll
                for (int j = 0; j < 4; ++j)
                    acc[i][j] += a.f[i]*b.f[j];
        }
    }
    #pragma unroll
    for (int i = 0; i < 4; ++i) {
        int r = row0 + ty*4 + i;
        int bb = r >> 11, sq = r & (SEQLEN-1);
        #pragma unroll
        for (int j = 0; j < 4; ++j) {
            int c = col0 + tx*4 + j;
            float val = acc[i][j] + bias[c];
            if (MODE == 0) {
                int h = c >> 6, d = c & 63;
                out[(((size_t)(bb*NHEADS + h))*SEQLEN + sq)*HEADD + d] = val;
            } else {
                out[(size_t)r*HDIM + c] = val + residual[(size_t)r*HDIM + c];
            }
        }
    }
}

// ---------- L2 normalize rows of 64 -> bf16 copy (input untouched) ----------
__global__ __launch_bounds__(256) void l2norm_cvt_kernel(
        const float* __restrict__ p, unsigned short* __restrict__ o) {
    size_t row = (size_t)blockIdx.x*4 + (threadIdx.x >> 6);
    int lane = threadIdx.x & 63;
    float val = p[row*64 + lane];
    float ss = val*val;
    #pragma unroll
    for (int off = 32; off > 0; off >>= 1) ss += __shfl_xor(ss, off);
    float sc = 1.0f / fmaxf(sqrtf(ss), 1e-12f);
    o[row*64 + lane] = f2bf(val * sc);
}

// ---------- transpose+cvt: v fp32 [bh][s][64] -> vt bf16 [bh][64][s] ----------
__global__ __launch_bounds__(256) void transpose_cvt_kernel(
        const float* __restrict__ v, unsigned short* __restrict__ vt) {
    __shared__ unsigned short T[64*72];   // row stride 72 shorts = 144B (16B-aligned)
    int bh = blockIdx.y, s0 = blockIdx.x*64;
    int t = threadIdx.x;
    #pragma unroll
    for (int it = 0; it < 4; ++it) {
        int r = (t>>4) + it*16;          // s-row 0..63
        int c = (t&15)*4;                // d col
        F4 x; x.v = *(const float4*)(v + ((size_t)bh*SEQLEN + s0 + r)*HEADD + c);
        #pragma unroll
        for (int j = 0; j < 4; ++j) T[(c+j)*72 + r] = f2bf(x.f[j]);
    }
    __syncthreads();
    #pragma unroll
    for (int it = 0; it < 2; ++it) {
        int d = (t>>3) + it*32;
        int ch = t&7;
        short8 rowv = *(const short8*)(T + d*72 + ch*8);
        *(short8*)(vt + ((size_t)bh*HEADD + d)*SEQLEN + s0 + ch*8) = rowv;
    }
}

// ---------------- MFMA flash attention step ----------------
// qg [bh][S][64] bf16 (query/state), kg [bh][S][64] bf16, vtg [bh][64][S] bf16
// OUTMODE 0: bf16 head-major out; 1: f32 [B][S][H] out
template<int OUTMODE>
__global__ __launch_bounds__(256) void attn_mfma_kernel(
        const unsigned short* __restrict__ qg, const unsigned short* __restrict__ kg,
        const unsigned short* __restrict__ vtg, void* __restrict__ outp) {
    __shared__ unsigned short Ks[64*64];      // [key][d], swizzled
    __shared__ unsigned short Vs[64*64];      // [d][key], swizzled
    __shared__ unsigned short Ps[4*16*64];    // per-wave P[q][key], swizzled
    int bh = blockIdx.y;
    int q0 = blockIdx.x * 64;
    int t = threadIdx.x;
    int wq = t >> 6;          // wave id: q-rows q0+wq*16..+15
    int l  = t & 63;
    int lq = l & 15;          // this lane's q (col in swapped layouts)
    int g  = l >> 4;          // 16-lane group
    // Q fragments (B-operand): lane needs Q[q0+wq*16+lq][dchunk*32 + g*8 .. +7]
    short8 qfrag[2];
    {
        const unsigned short* qrow = qg + ((size_t)bh*SEQLEN + q0 + wq*16 + lq)*HEADD;
        qfrag[0] = *(const short8*)(qrow + g*8);
        qfrag[1] = *(const short8*)(qrow + 32 + g*8);
    }
    f32x4 oacc[4];                 // O^T[d][q]: d = ds*16 + g*4 + i, q = lq
    #pragma unroll
    for (int ds = 0; ds < 4; ++ds) oacc[ds] = 0.0f;
    float lsum = 0.0f;
    float m = -1e30f;
    const unsigned short* Kbase = kg + (size_t)bh*SEQLEN*HEADD;
    const unsigned short* Vbase = vtg + (size_t)bh*HEADD*SEQLEN;
    unsigned short* Pw = Ps + wq*16*64;

    for (int kt = 0; kt < SEQLEN/64; ++kt) {
        __syncthreads();     // previous tile's LDS reads complete
        #pragma unroll
        for (int p = 0; p < 2; ++p) {
            int idx = t + 256*p;
            int r = idx >> 3;                     // row 0..63
            int c = idx & 7;                      // 16B chunk
            int sw = (c*16) ^ ((r&7)<<4);
            short8 kv = *(const short8*)(Kbase + (size_t)(kt*64 + r)*HEADD + c*8);
            *(short8*)((char*)Ks + r*128 + sw) = kv;
            short8 vv = *(const short8*)(Vbase + (size_t)r*SEQLEN + kt*64 + c*8);
            *(short8*)((char*)Vs + r*128 + sw) = vv;
        }
        __syncthreads();
        // ---- QK^T (swapped): sim^T[key][q], key = ks*16 + g*4 + i ----
        f32x4 sim[4];
        #pragma unroll
        for (int ks = 0; ks < 4; ++ks) sim[ks] = 0.0f;
        #pragma unroll
        for (int dc = 0; dc < 2; ++dc) {
            #pragma unroll
            for (int ks = 0; ks < 4; ++ks) {
                int row = ks*16 + lq;
                short8 kf = *(const short8*)((char*)Ks + row*128 + ((dc*64 + g*16) ^ ((row&7)<<4)));
                sim[ks] = __builtin_amdgcn_mfma_f32_16x16x32_bf16(kf, qfrag[dc], sim[ks], 0, 0, 0);
            }
        }
        // ---- online softmax (deferred-max, threshold 8) ----
        float tm = -1e30f;
        #pragma unroll
        for (int ks = 0; ks < 4; ++ks)
            #pragma unroll
            for (int i = 0; i < 4; ++i) tm = fmaxf(tm, sim[ks][i]);
        tm = fmaxf(tm, __shfl_xor(tm, 16));
        tm = fmaxf(tm, __shfl_xor(tm, 32));
        if (!__all(tm <= m + 8.0f)) {
            float mn = fmaxf(m, tm);
            float sc = __expf(m - mn);
            #pragma unroll
            for (int ds = 0; ds < 4; ++ds)
                #pragma unroll
                for (int i = 0; i < 4; ++i) oacc[ds][i] *= sc;
            lsum *= sc;
            m = mn;
        }
        #pragma unroll
        for (int ks = 0; ks < 4; ++ks) {
            us4v pk;
            #pragma unroll
            for (int i = 0; i < 4; ++i) {
                float pv = __expf(sim[ks][i] - m);
                lsum += pv;
                pk[i] = f2bf(pv);
            }
            *(us4v*)((char*)Pw + lq*128 + ((ks*32 + g*8) ^ ((lq&7)<<4))) = pk;
        }
        // ---- PV (swapped): O^T[d][q] += Vt[d][k] * P^T[k][q] ----
        #pragma unroll
        for (int kc = 0; kc < 2; ++kc) {
            short8 pf = *(const short8*)((char*)Pw + lq*128 + ((kc*64 + g*16) ^ ((lq&7)<<4)));
            #pragma unroll
            for (int ds = 0; ds < 4; ++ds) {
                int row = ds*16 + lq;
                short8 vf = *(const short8*)((char*)Vs + row*128 + ((kc*64 + g*16) ^ ((row&7)<<4)));
                oacc[ds] = __builtin_amdgcn_mfma_f32_16x16x32_bf16(vf, pf, oacc[ds], 0, 0, 0);
            }
        }
    }
    // ---- epilogue ----
    lsum += __shfl_xor(lsum, 16);
    lsum += __shfl_xor(lsum, 32);
    float inv = 1.0f / lsum;
    int row = q0 + wq*16 + lq;
    if (OUTMODE == 0) {
        unsigned short* o = (unsigned short*)outp + ((size_t)bh*SEQLEN + row)*HEADD;
        #pragma unroll
        for (int ds = 0; ds < 4; ++ds) {
            us4v pk;
            #pragma unroll
            for (int i = 0; i < 4; ++i) pk[i] = f2bf(oacc[ds][i] * inv);
            *(us4v*)(o + ds*16 + g*4) = pk;
        }
    } else {
        float* o = (float*)outp;
        int bb = bh >> 4, h = bh & 15;
        #pragma unroll
        for (int ds = 0; ds < 4; ++ds) {
            F4 ov;
            #pragma unroll
            for (int i = 0; i < 4; ++i) ov.f[i] = oacc[ds][i] * inv;
            *(float4*)(o + ((size_t)bb*SEQLEN + row)*HDIM + h*HEADD + ds*16 + g*4) = ov.v;
        }
    }
}

extern "C" void kernel_launch(void* const* d_in, const int* in_sizes, int n_in,
                              void* d_out, int out_size, void* d_ws, size_t ws_size,
                              hipStream_t stream) {
    const float* hs = (const float*)d_in[0];
    const float* Wq = (const float*)d_in[1];
    const float* bq = (const float*)d_in[2];
    const float* Wk = (const float*)d_in[3];
    const float* bk = (const float*)d_in[4];
    const float* Wv = (const float*)d_in[5];
    const float* bv = (const float*)d_in[6];
    const float* Wo = (const float*)d_in[7];
    const float* bo = (const float*)d_in[8];
    const float* lw = (const float*)d_in[9];
    const float* lb = (const float*)d_in[10];
    float* out = (float*)d_out;
    float* ws = (float*)d_ws;
    const size_t NE = (size_t)NROWS * HDIM;      // 4.19M elements
    float* xn = ws;                              // slot0: post-LN, later s2
    float* qf = ws + NE;                         // slot1: q fp32, later vt+s1
    float* kf = ws + 2*NE;                       // slot2
    float* vf = ws + 3*NE;                       // slot3
    unsigned short* qb = (unsigned short*)(ws + 4*NE);  // slot4 lower (bf16)
    unsigned short* kb = qb + NE;                       // slot4 upper (bf16)
    unsigned short* vt = (unsigned short*)qf;           // slot1 lower (qf dead)
    unsigned short* s1 = (unsigned short*)qf + NE;      // slot1 upper
    float* s2 = xn;                                     // slot0 (xn dead)

    ln_kernel<<<NROWS, 256, 0, stream>>>(hs, lw, lb, xn);
    dim3 gg(NROWS/64, HDIM/64);
    gemm_kernel<0><<<gg, 256, 0, stream>>>(xn, Wq, bq, nullptr, qf);
    gemm_kernel<0><<<gg, 256, 0, stream>>>(xn, Wk, bk, nullptr, kf);
    gemm_kernel<0><<<gg, 256, 0, stream>>>(xn, Wv, bv, nullptr, vf);
    int nrows64 = NROWS * NHEADS;
    l2norm_cvt_kernel<<<nrows64/4, 256, 0, stream>>>(qf, qb);
    l2norm_cvt_kernel<<<nrows64/4, 256, 0, stream>>>(kf, kb);
    transpose_cvt_kernel<<<dim3(SEQLEN/64, NBH), 256, 0, stream>>>(vf, vt);
    dim3 ag(SEQLEN/64, NBH);
    attn_mfma_kernel<0><<<ag, 256, 0, stream>>>(qb, kb, vt, s1);
    attn_mfma_kernel<1><<<ag, 256, 0, stream>>>(s1, kb, vt, s2);
    gemm_kernel<1><<<gg, 256, 0, stream>>>(s2, Wo, bo, hs, out);
}

// Round 3
// 251.357 us; speedup vs baseline: 11.3940x; 2.7917x over previous
//
#include <hip/hip_runtime.h>
#include <hip/hip_bf16.h>
#include <math.h>

#define HDIM 1024
#define NHEADS 16
#define HEADD 64
#define SEQLEN 2048
#define NBATCH 2
#define NROWS (NBATCH*SEQLEN)
#define NBH (NBATCH*NHEADS)

typedef float f32x4 __attribute__((ext_vector_type(4)));
typedef short short8 __attribute__((ext_vector_type(8)));
typedef unsigned short us4v __attribute__((ext_vector_type(4)));

#define GLOBAL_AS __attribute__((address_space(1)))
#define LDS_AS __attribute__((address_space(3)))

union F4 { float4 v; float f[4]; };

static __device__ __forceinline__ unsigned short f2bf(float x) {
    __hip_bfloat16 h = __float2bfloat16(x);
    return *(unsigned short*)&h;
}

// ---------------- LayerNorm -> bf16 ----------------
__global__ __launch_bounds__(256) void ln_kernel(
        const float* __restrict__ x, const float* __restrict__ w,
        const float* __restrict__ b, unsigned short* __restrict__ xn) {
    int row = blockIdx.x;
    F4 vv; vv.v = ((const float4*)(x + (size_t)row*HDIM))[threadIdx.x];
    float s  = vv.f[0]+vv.f[1]+vv.f[2]+vv.f[3];
    float ss = vv.f[0]*vv.f[0]+vv.f[1]*vv.f[1]+vv.f[2]*vv.f[2]+vv.f[3]*vv.f[3];
    #pragma unroll
    for (int off = 32; off > 0; off >>= 1) {
        s  += __shfl_xor(s, off);
        ss += __shfl_xor(ss, off);
    }
    __shared__ float red[8];
    int wid = threadIdx.x >> 6;
    if ((threadIdx.x & 63) == 0) { red[wid] = s; red[wid+4] = ss; }
    __syncthreads();
    s  = red[0]+red[1]+red[2]+red[3];
    ss = red[4]+red[5]+red[6]+red[7];
    float mean = s * (1.0f/HDIM);
    float var  = ss * (1.0f/HDIM) - mean*mean;
    float rstd = rsqrtf(var + 1e-5f);
    F4 wv; wv.v = ((const float4*)w)[threadIdx.x];
    F4 bv; bv.v = ((const float4*)b)[threadIdx.x];
    us4v o;
    #pragma unroll
    for (int j = 0; j < 4; ++j)
        o[j] = f2bf((vv.f[j]-mean)*rstd*wv.f[j] + bv.f[j]);
    *(us4v*)(xn + (size_t)row*HDIM + threadIdx.x*4) = o;
}

// ---------- weight convert+transpose: W[k][n] f32 -> Wt[n][k] bf16 ----------
__global__ __launch_bounds__(256) void wconv_kernel(
        const float* __restrict__ W, unsigned short* __restrict__ Wt) {
    __shared__ unsigned short T[64*72];
    int k0 = blockIdx.x*64, n0 = blockIdx.y*64;
    int t = threadIdx.x;
    #pragma unroll
    for (int it = 0; it < 4; ++it) {
        int r = (t>>4) + it*16;          // k
        int c = (t&15)*4;                // n
        F4 x; x.v = *(const float4*)(W + (size_t)(k0+r)*HDIM + n0 + c);
        #pragma unroll
        for (int j = 0; j < 4; ++j) T[(c+j)*72 + r] = f2bf(x.f[j]);
    }
    __syncthreads();
    #pragma unroll
    for (int it = 0; it < 2; ++it) {
        int n = (t>>3) + it*32;
        int ch = t&7;
        short8 rowv = *(const short8*)(T + n*72 + ch*8);
        *(short8*)(Wt + (size_t)(n0+n)*HDIM + k0 + ch*8) = rowv;
    }
}

// ---------------- bf16 MFMA GEMM: C = A @ Wt^T (+bias) ----------------
// MODE 0: +bias, L2-normalize per head-row, write bf16 head-major [bh][s][64]
// MODE 1: +bias, write bf16 transposed [bh][64][s]   (for V)
// MODE 2: +bias +residual, write f32 row-major [m][1024]
template<int MODE>
__global__ __launch_bounds__(256) void gemm_mfma_kernel(
        const unsigned short* __restrict__ A,
        const unsigned short* __restrict__ Wt,
        const float* __restrict__ bias,
        const float* __restrict__ residual,
        void* __restrict__ outp) {
    __shared__ unsigned short As[128*64];   // linear dest, source-swizzled chunks
    __shared__ unsigned short Bs[128*64];
    int m0 = blockIdx.x * 128;
    int n0 = blockIdx.y * 128;
    int t = threadIdx.x;
    int wid = t >> 6, l = t & 63;
    int wm = wid >> 1, wn = wid & 1;
    int lq = l & 15, g = l >> 4;
    f32x4 acc[4][4];
    #pragma unroll
    for (int mi = 0; mi < 4; ++mi)
        #pragma unroll
        for (int ni = 0; ni < 4; ++ni) acc[mi][ni] = 0.0f;
    for (int k0 = 0; k0 < HDIM; k0 += 64) {
        __syncthreads();
        #pragma unroll
        for (int i = 0; i < 4; ++i) {
            int idx = t + 256*i;
            int r = idx >> 3, ch = idx & 7;
            int gch = ch ^ (r & 7);           // pre-swizzled global source
            __builtin_amdgcn_global_load_lds(
                (const GLOBAL_AS void*)(A + (size_t)(m0+r)*HDIM + k0 + gch*8),
                (LDS_AS void*)((char*)As + idx*16), 16, 0, 0);
            __builtin_amdgcn_global_load_lds(
                (const GLOBAL_AS void*)(Wt + (size_t)(n0+r)*HDIM + k0 + gch*8),
                (LDS_AS void*)((char*)Bs + idx*16), 16, 0, 0);
        }
        __syncthreads();
        #pragma unroll
        for (int kc = 0; kc < 2; ++kc) {
            short8 af[4], bf[4];
            #pragma unroll
            for (int mi = 0; mi < 4; ++mi) {
                int r = wm*64 + mi*16 + lq;
                af[mi] = *(const short8*)((char*)As + r*128 + (((kc*4+g) ^ (r&7))<<4));
            }
            #pragma unroll
            for (int ni = 0; ni < 4; ++ni) {
                int r = wn*64 + ni*16 + lq;
                bf[ni] = *(const short8*)((char*)Bs + r*128 + (((kc*4+g) ^ (r&7))<<4));
            }
            #pragma unroll
            for (int mi = 0; mi < 4; ++mi)
                #pragma unroll
                for (int ni = 0; ni < 4; ++ni)
                    acc[mi][ni] = __builtin_amdgcn_mfma_f32_16x16x32_bf16(
                        af[mi], bf[ni], acc[mi][ni], 0, 0, 0);
        }
    }
    // -------- epilogue --------
    float bv[4];
    #pragma unroll
    for (int ni = 0; ni < 4; ++ni) bv[ni] = bias[n0 + wn*64 + ni*16 + lq];
    #pragma unroll
    for (int mi = 0; mi < 4; ++mi)
        #pragma unroll
        for (int ni = 0; ni < 4; ++ni)
            #pragma unroll
            for (int i = 0; i < 4; ++i) acc[mi][ni][i] += bv[ni];
    if (MODE == 0) {
        int h = (n0 >> 6) + wn;
        #pragma unroll
        for (int mi = 0; mi < 4; ++mi) {
            f32x4 ss = 0.0f;
            #pragma unroll
            for (int ni = 0; ni < 4; ++ni)
                #pragma unroll
                for (int i = 0; i < 4; ++i) ss[i] += acc[mi][ni][i]*acc[mi][ni][i];
            #pragma unroll
            for (int off = 1; off < 16; off <<= 1)
                #pragma unroll
                for (int i = 0; i < 4; ++i) ss[i] += __shfl_xor(ss[i], off);
            #pragma unroll
            for (int i = 0; i < 4; ++i) {
                float sc = 1.0f / fmaxf(sqrtf(ss[i]), 1e-12f);
                int m = m0 + wm*64 + mi*16 + g*4 + i;
                int bb = m >> 11, sq = m & (SEQLEN-1);
                unsigned short* orow = (unsigned short*)outp
                    + ((size_t)(bb*NHEADS + h)*SEQLEN + sq)*HEADD;
                #pragma unroll
                for (int ni = 0; ni < 4; ++ni)
                    orow[ni*16 + lq] = f2bf(acc[mi][ni][i] * sc);
            }
        }
    } else if (MODE == 1) {
        int h = (n0 >> 6) + wn;
        #pragma unroll
        for (int mi = 0; mi < 4; ++mi) {
            int m = m0 + wm*64 + mi*16 + g*4;
            int bb = m >> 11, sq = m & (SEQLEN-1);
            #pragma unroll
            for (int ni = 0; ni < 4; ++ni) {
                int d = ni*16 + lq;
                us4v pk;
                #pragma unroll
                for (int i = 0; i < 4; ++i) pk[i] = f2bf(acc[mi][ni][i]);
                *(us4v*)((unsigned short*)outp
                    + ((size_t)(bb*NHEADS + h)*HEADD + d)*SEQLEN + sq) = pk;
            }
        }
    } else {
        #pragma unroll
        for (int mi = 0; mi < 4; ++mi)
            #pragma unroll
            for (int i = 0; i < 4; ++i) {
                int m = m0 + wm*64 + mi*16 + g*4 + i;
                float* orow = (float*)outp + (size_t)m*HDIM;
                const float* rrow = residual + (size_t)m*HDIM;
                #pragma unroll
                for (int ni = 0; ni < 4; ++ni) {
                    int n = n0 + wn*64 + ni*16 + lq;
                    orow[n] = acc[mi][ni][i] + rrow[n];
                }
            }
    }
}

// ---------------- MFMA flash attention step ----------------
// qg [bh][S][64] bf16, kg [bh][S][64] bf16, vtg [bh][64][S] bf16
// OUTMODE 0: bf16 head-major out; 1: bf16 [B][S][H] out
template<int OUTMODE>
__global__ __launch_bounds__(256) void attn_mfma_kernel(
        const unsigned short* __restrict__ qg, const unsigned short* __restrict__ kg,
        const unsigned short* __restrict__ vtg, void* __restrict__ outp) {
    __shared__ unsigned short Ks[64*64];
    __shared__ unsigned short Vs[64*64];
    __shared__ unsigned short Ps[4*16*64];
    int bh = blockIdx.y;
    int q0 = blockIdx.x * 64;
    int t = threadIdx.x;
    int wq = t >> 6;
    int l  = t & 63;
    int lq = l & 15;
    int g  = l >> 4;
    short8 qfrag[2];
    {
        const unsigned short* qrow = qg + ((size_t)bh*SEQLEN + q0 + wq*16 + lq)*HEADD;
        qfrag[0] = *(const short8*)(qrow + g*8);
        qfrag[1] = *(const short8*)(qrow + 32 + g*8);
    }
    f32x4 oacc[4];
    #pragma unroll
    for (int ds = 0; ds < 4; ++ds) oacc[ds] = 0.0f;
    float lsum = 0.0f;
    float m = -1e30f;
    const unsigned short* Kbase = kg + (size_t)bh*SEQLEN*HEADD;
    const unsigned short* Vbase = vtg + (size_t)bh*HEADD*SEQLEN;
    unsigned short* Pw = Ps + wq*16*64;

    for (int kt = 0; kt < SEQLEN/64; ++kt) {
        __syncthreads();
        #pragma unroll
        for (int p = 0; p < 2; ++p) {
            int idx = t + 256*p;
            int r = idx >> 3;
            int c = idx & 7;
            int sw = (c*16) ^ ((r&7)<<4);
            short8 kv = *(const short8*)(Kbase + (size_t)(kt*64 + r)*HEADD + c*8);
            *(short8*)((char*)Ks + r*128 + sw) = kv;
            short8 vv = *(const short8*)(Vbase + (size_t)r*SEQLEN + kt*64 + c*8);
            *(short8*)((char*)Vs + r*128 + sw) = vv;
        }
        __syncthreads();
        f32x4 sim[4];
        #pragma unroll
        for (int ks = 0; ks < 4; ++ks) sim[ks] = 0.0f;
        #pragma unroll
        for (int dc = 0; dc < 2; ++dc) {
            #pragma unroll
            for (int ks = 0; ks < 4; ++ks) {
                int row = ks*16 + lq;
                short8 kf = *(const short8*)((char*)Ks + row*128 + ((dc*64 + g*16) ^ ((row&7)<<4)));
                sim[ks] = __builtin_amdgcn_mfma_f32_16x16x32_bf16(kf, qfrag[dc], sim[ks], 0, 0, 0);
            }
        }
        float tm = -1e30f;
        #pragma unroll
        for (int ks = 0; ks < 4; ++ks)
            #pragma unroll
            for (int i = 0; i < 4; ++i) tm = fmaxf(tm, sim[ks][i]);
        tm = fmaxf(tm, __shfl_xor(tm, 16));
        tm = fmaxf(tm, __shfl_xor(tm, 32));
        if (!__all(tm <= m + 8.0f)) {
            float mn = fmaxf(m, tm);
            float sc = __expf(m - mn);
            #pragma unroll
            for (int ds = 0; ds < 4; ++ds)
                #pragma unroll
                for (int i = 0; i < 4; ++i) oacc[ds][i] *= sc;
            lsum *= sc;
            m = mn;
        }
        #pragma unroll
        for (int ks = 0; ks < 4; ++ks) {
            us4v pk;
            #pragma unroll
            for (int i = 0; i < 4; ++i) {
                float pv = __expf(sim[ks][i] - m);
                lsum += pv;
                pk[i] = f2bf(pv);
            }
            *(us4v*)((char*)Pw + lq*128 + ((ks*32 + g*8) ^ ((lq&7)<<4))) = pk;
        }
        #pragma unroll
        for (int kc = 0; kc < 2; ++kc) {
            short8 pf = *(const short8*)((char*)Pw + lq*128 + ((kc*64 + g*16) ^ ((lq&7)<<4)));
            #pragma unroll
            for (int ds = 0; ds < 4; ++ds) {
                int row = ds*16 + lq;
                short8 vf = *(const short8*)((char*)Vs + row*128 + ((kc*64 + g*16) ^ ((row&7)<<4)));
                oacc[ds] = __builtin_amdgcn_mfma_f32_16x16x32_bf16(vf, pf, oacc[ds], 0, 0, 0);
            }
        }
    }
    lsum += __shfl_xor(lsum, 16);
    lsum += __shfl_xor(lsum, 32);
    float inv = 1.0f / lsum;
    int row = q0 + wq*16 + lq;
    if (OUTMODE == 0) {
        unsigned short* o = (unsigned short*)outp + ((size_t)bh*SEQLEN + row)*HEADD;
        #pragma unroll
        for (int ds = 0; ds < 4; ++ds) {
            us4v pk;
            #pragma unroll
            for (int i = 0; i < 4; ++i) pk[i] = f2bf(oacc[ds][i] * inv);
            *(us4v*)(o + ds*16 + g*4) = pk;
        }
    } else {
        unsigned short* o = (unsigned short*)outp;
        int bb = bh >> 4, h = bh & 15;
        #pragma unroll
        for (int ds = 0; ds < 4; ++ds) {
            us4v pk;
            #pragma unroll
            for (int i = 0; i < 4; ++i) pk[i] = f2bf(oacc[ds][i] * inv);
            *(us4v*)(o + ((size_t)bb*SEQLEN + row)*HDIM + h*HEADD + ds*16 + g*4) = pk;
        }
    }
}

extern "C" void kernel_launch(void* const* d_in, const int* in_sizes, int n_in,
                              void* d_out, int out_size, void* d_ws, size_t ws_size,
                              hipStream_t stream) {
    const float* hs = (const float*)d_in[0];
    const float* Wq = (const float*)d_in[1];
    const float* bq = (const float*)d_in[2];
    const float* Wk = (const float*)d_in[3];
    const float* bk = (const float*)d_in[4];
    const float* Wv = (const float*)d_in[5];
    const float* bv = (const float*)d_in[6];
    const float* Wo = (const float*)d_in[7];
    const float* bo = (const float*)d_in[8];
    const float* lw = (const float*)d_in[9];
    const float* lb = (const float*)d_in[10];
    float* out = (float*)d_out;
    unsigned short* ws16 = (unsigned short*)d_ws;
    const size_t NE = (size_t)NROWS * HDIM;   // 4.19M elements
    const size_t WE = (size_t)HDIM * HDIM;    // 1.05M elements
    unsigned short* xn  = ws16;
    unsigned short* Wtq = xn + NE;
    unsigned short* Wtk = Wtq + WE;
    unsigned short* Wtv = Wtk + WE;
    unsigned short* Wto = Wtv + WE;
    unsigned short* qb  = Wto + WE;
    unsigned short* kb  = qb + NE;
    unsigned short* vt  = kb + NE;
    unsigned short* s1  = vt + NE;
    unsigned short* s2  = s1 + NE;   // total ~58.8 MB

    ln_kernel<<<NROWS, 256, 0, stream>>>(hs, lw, lb, xn);
    dim3 wg(HDIM/64, HDIM/64);
    wconv_kernel<<<wg, 256, 0, stream>>>(Wq, Wtq);
    wconv_kernel<<<wg, 256, 0, stream>>>(Wk, Wtk);
    wconv_kernel<<<wg, 256, 0, stream>>>(Wv, Wtv);
    wconv_kernel<<<wg, 256, 0, stream>>>(Wo, Wto);
    dim3 gg(NROWS/128, HDIM/128);
    gemm_mfma_kernel<0><<<gg, 256, 0, stream>>>(xn, Wtq, bq, nullptr, qb);
    gemm_mfma_kernel<0><<<gg, 256, 0, stream>>>(xn, Wtk, bk, nullptr, kb);
    gemm_mfma_kernel<1><<<gg, 256, 0, stream>>>(xn, Wtv, bv, nullptr, vt);
    dim3 ag(SEQLEN/64, NBH);
    attn_mfma_kernel<0><<<ag, 256, 0, stream>>>(qb, kb, vt, s1);
    attn_mfma_kernel<1><<<ag, 256, 0, stream>>>(s1, kb, vt, s2);
    gemm_mfma_kernel<2><<<gg, 256, 0, stream>>>(s2, Wto, bo, hs, out);
}

// Round 5
// 223.923 us; speedup vs baseline: 12.7899x; 1.1225x over previous
//
#include <hip/hip_runtime.h>
#include <hip/hip_bf16.h>
#include <math.h>

#define HDIM 1024
#define NHEADS 16
#define HEADD 64
#define SEQLEN 2048
#define NBATCH 2
#define NROWS (NBATCH*SEQLEN)
#define NBH (NBATCH*NHEADS)
#define LOG2E 1.44269504f

typedef float f32x4 __attribute__((ext_vector_type(4)));
typedef float f32x16 __attribute__((ext_vector_type(16)));
typedef short short8 __attribute__((ext_vector_type(8)));
typedef unsigned short us4v __attribute__((ext_vector_type(4)));

#define GLOBAL_AS __attribute__((address_space(1)))
#define LDS_AS __attribute__((address_space(3)))

union F4 { float4 v; float f[4]; };
union PW { unsigned int u[4]; short8 s; };

static __device__ __forceinline__ unsigned short f2bf(float x) {
    __hip_bfloat16 h = __float2bfloat16(x);
    return *(unsigned short*)&h;
}

// ---------------- LayerNorm -> bf16 ----------------
__global__ __launch_bounds__(256) void ln_kernel(
        const float* __restrict__ x, const float* __restrict__ w,
        const float* __restrict__ b, unsigned short* __restrict__ xn) {
    int row = blockIdx.x;
    F4 vv; vv.v = ((const float4*)(x + (size_t)row*HDIM))[threadIdx.x];
    float s  = vv.f[0]+vv.f[1]+vv.f[2]+vv.f[3];
    float ss = vv.f[0]*vv.f[0]+vv.f[1]*vv.f[1]+vv.f[2]*vv.f[2]+vv.f[3]*vv.f[3];
    #pragma unroll
    for (int off = 32; off > 0; off >>= 1) {
        s  += __shfl_xor(s, off);
        ss += __shfl_xor(ss, off);
    }
    __shared__ float red[8];
    int wid = threadIdx.x >> 6;
    if ((threadIdx.x & 63) == 0) { red[wid] = s; red[wid+4] = ss; }
    __syncthreads();
    s  = red[0]+red[1]+red[2]+red[3];
    ss = red[4]+red[5]+red[6]+red[7];
    float mean = s * (1.0f/HDIM);
    float var  = ss * (1.0f/HDIM) - mean*mean;
    float rstd = rsqrtf(var + 1e-5f);
    F4 wv; wv.v = ((const float4*)w)[threadIdx.x];
    F4 bv; bv.v = ((const float4*)b)[threadIdx.x];
    us4v o;
    #pragma unroll
    for (int j = 0; j < 4; ++j)
        o[j] = f2bf((vv.f[j]-mean)*rstd*wv.f[j] + bv.f[j]);
    *(us4v*)(xn + (size_t)row*HDIM + threadIdx.x*4) = o;
}

// ---------- weight convert+transpose: W[k][n] f32 -> Wt[n][k] bf16 ----------
__global__ __launch_bounds__(256) void wconv_kernel(
        const float* __restrict__ W, unsigned short* __restrict__ Wt) {
    __shared__ unsigned short T[64*72];
    int k0 = blockIdx.x*64, n0 = blockIdx.y*64;
    int t = threadIdx.x;
    #pragma unroll
    for (int it = 0; it < 4; ++it) {
        int r = (t>>4) + it*16;
        int c = (t&15)*4;
        F4 x; x.v = *(const float4*)(W + (size_t)(k0+r)*HDIM + n0 + c);
        #pragma unroll
        for (int j = 0; j < 4; ++j) T[(c+j)*72 + r] = f2bf(x.f[j]);
    }
    __syncthreads();
    #pragma unroll
    for (int it = 0; it < 2; ++it) {
        int n = (t>>3) + it*32;
        int ch = t&7;
        short8 rowv = *(const short8*)(T + n*72 + ch*8);
        *(short8*)(Wt + (size_t)(n0+n)*HDIM + k0 + ch*8) = rowv;
    }
}

// ---------------- bf16 MFMA GEMM: C = A @ Wt^T (+bias), 2-phase dbuf ----------------
// MODE 0: +bias, L2-normalize per head-row ×oscale, write bf16 head-major [bh][s][64]
// MODE 1: +bias, write bf16 transposed [bh][64][s]   (for V)
// MODE 2: +bias +residual, write f32 row-major [m][1024]
template<int MODE>
__global__ __launch_bounds__(256) void gemm_mfma_kernel(
        const unsigned short* __restrict__ A,
        const unsigned short* __restrict__ Wt,
        const float* __restrict__ bias,
        const float* __restrict__ residual,
        void* __restrict__ outp, float oscale) {
    __shared__ unsigned short As[2][128*64];
    __shared__ unsigned short Bs[2][128*64];
    int m0 = blockIdx.x * 128;
    int n0 = blockIdx.y * 128;
    int t = threadIdx.x;
    int wid = t >> 6, l = t & 63;
    int wm = wid >> 1, wn = wid & 1;
    int lq = l & 15, g = l >> 4;
    f32x4 acc[4][4];
    #pragma unroll
    for (int mi = 0; mi < 4; ++mi)
        #pragma unroll
        for (int ni = 0; ni < 4; ++ni) acc[mi][ni] = 0.0f;

    auto STAGE = [&](int b, int k0) {
        #pragma unroll
        for (int i = 0; i < 4; ++i) {
            int idx = t + 256*i;
            int r = idx >> 3, ch = idx & 7;
            int gch = ch ^ (r & 7);
            __builtin_amdgcn_global_load_lds(
                (const GLOBAL_AS void*)(A + (size_t)(m0+r)*HDIM + k0 + gch*8),
                (LDS_AS void*)((char*)&As[b][0] + idx*16), 16, 0, 0);
            __builtin_amdgcn_global_load_lds(
                (const GLOBAL_AS void*)(Wt + (size_t)(n0+r)*HDIM + k0 + gch*8),
                (LDS_AS void*)((char*)&Bs[b][0] + idx*16), 16, 0, 0);
        }
    };

    STAGE(0, 0);
    asm volatile("s_waitcnt vmcnt(0)" ::: "memory");
    __builtin_amdgcn_s_barrier();
    asm volatile("" ::: "memory");
    int buf = 0;
    for (int ks = 0; ks < 16; ++ks) {
        if (ks < 15) STAGE(buf^1, (ks+1)*64);
        const char* Ab = (const char*)&As[buf][0];
        const char* Bb = (const char*)&Bs[buf][0];
        #pragma unroll
        for (int kc = 0; kc < 2; ++kc) {
            short8 af[4], bf[4];
            #pragma unroll
            for (int mi = 0; mi < 4; ++mi) {
                int r = wm*64 + mi*16 + lq;
                af[mi] = *(const short8*)(Ab + r*128 + (((kc*4+g) ^ (r&7))<<4));
            }
            #pragma unroll
            for (int ni = 0; ni < 4; ++ni) {
                int r = wn*64 + ni*16 + lq;
                bf[ni] = *(const short8*)(Bb + r*128 + (((kc*4+g) ^ (r&7))<<4));
            }
            #pragma unroll
            for (int mi = 0; mi < 4; ++mi)
                #pragma unroll
                for (int ni = 0; ni < 4; ++ni)
                    acc[mi][ni] = __builtin_amdgcn_mfma_f32_16x16x32_bf16(
                        af[mi], bf[ni], acc[mi][ni], 0, 0, 0);
        }
        asm volatile("s_waitcnt vmcnt(0)" ::: "memory");
        __builtin_amdgcn_s_barrier();
        asm volatile("" ::: "memory");
        buf ^= 1;
    }
    // -------- epilogue --------
    float bv[4];
    #pragma unroll
    for (int ni = 0; ni < 4; ++ni) bv[ni] = bias[n0 + wn*64 + ni*16 + lq];
    #pragma unroll
    for (int mi = 0; mi < 4; ++mi)
        #pragma unroll
        for (int ni = 0; ni < 4; ++ni)
            #pragma unroll
            for (int i = 0; i < 4; ++i) acc[mi][ni][i] += bv[ni];
    if (MODE == 0) {
        int h = (n0 >> 6) + wn;
        #pragma unroll
        for (int mi = 0; mi < 4; ++mi) {
            f32x4 ss = 0.0f;
            #pragma unroll
            for (int ni = 0; ni < 4; ++ni)
                #pragma unroll
                for (int i = 0; i < 4; ++i) ss[i] += acc[mi][ni][i]*acc[mi][ni][i];
            #pragma unroll
            for (int off = 1; off < 16; off <<= 1)
                #pragma unroll
                for (int i = 0; i < 4; ++i) ss[i] += __shfl_xor(ss[i], off);
            #pragma unroll
            for (int i = 0; i < 4; ++i) {
                float sc = oscale / fmaxf(sqrtf(ss[i]), 1e-12f);
                int m = m0 + wm*64 + mi*16 + g*4 + i;
                int bb = m >> 11, sq = m & (SEQLEN-1);
                unsigned short* orow = (unsigned short*)outp
                    + ((size_t)(bb*NHEADS + h)*SEQLEN + sq)*HEADD;
                #pragma unroll
                for (int ni = 0; ni < 4; ++ni)
                    orow[ni*16 + lq] = f2bf(acc[mi][ni][i] * sc);
            }
        }
    } else if (MODE == 1) {
        int h = (n0 >> 6) + wn;
        #pragma unroll
        for (int mi = 0; mi < 4; ++mi) {
            int m = m0 + wm*64 + mi*16 + g*4;
            int bb = m >> 11, sq = m & (SEQLEN-1);
            #pragma unroll
            for (int ni = 0; ni < 4; ++ni) {
                int d = ni*16 + lq;
                us4v pk;
                #pragma unroll
                for (int i = 0; i < 4; ++i) pk[i] = f2bf(acc[mi][ni][i]);
                *(us4v*)((unsigned short*)outp
                    + ((size_t)(bb*NHEADS + h)*HEADD + d)*SEQLEN + sq) = pk;
            }
        }
    } else {
        #pragma unroll
        for (int mi = 0; mi < 4; ++mi)
            #pragma unroll
            for (int i = 0; i < 4; ++i) {
                int m = m0 + wm*64 + mi*16 + g*4 + i;
                float* orow = (float*)outp + (size_t)m*HDIM;
                const float* rrow = residual + (size_t)m*HDIM;
                #pragma unroll
                for (int ni = 0; ni < 4; ++ni) {
                    int n = n0 + wn*64 + ni*16 + lq;
                    orow[n] = acc[mi][ni][i] + rrow[n];
                }
            }
    }
}

// ---------------- 32x32-MFMA flash attention, P-in-register ----------------
// qg: queries/state bf16 [bh][S][64], PRE-SCALED by log2(e)
// kg: keys bf16 [bh][S][64] (unit rows); vtg: V^T bf16 [bh][64][S]
// OUTMODE 0: bf16 head-major out ×log2e (state for next step)
// OUTMODE 1: bf16 [B][S][H] out (unscaled)
template<int OUTMODE>
__global__ __launch_bounds__(256, 2) void attn2_kernel(
        const unsigned short* __restrict__ qg, const unsigned short* __restrict__ kg,
        const unsigned short* __restrict__ vtg, unsigned short* __restrict__ outp) {
    // L[buf][ K(8KB) | V(8KB) ]  = 32 KiB
    __shared__ unsigned short L[2][2*4096];
    int bh = blockIdx.y;
    int q0 = blockIdx.x * 128;
    int t = threadIdx.x;
    int wq = t >> 6, l = t & 63;
    int q = l & 31, hi = l >> 5, r7 = q & 7;
    // Q fragments (B-operand): Q[q0+wq*32+q][dc*16 + hi*8 + j]
    short8 qf[4];
    {
        const unsigned short* qrow = qg + ((size_t)bh*SEQLEN + q0 + wq*32 + q)*HEADD;
        #pragma unroll
        for (int dc = 0; dc < 4; ++dc) qf[dc] = *(const short8*)(qrow + dc*16 + hi*8);
    }
    // loop-invariant LDS read offsets (same table serves K's dc and V's c)
    int koffv[4];
    #pragma unroll
    for (int x = 0; x < 4; ++x) koffv[x] = q*128 + (((x*2 + hi) ^ r7) << 4);

    f32x16 oacc0 = 0.0f, oacc1 = 0.0f;
    float lsum = 0.0f;
    const unsigned short* Kg = kg + (size_t)bh*SEQLEN*HEADD;
    const unsigned short* Vg = vtg + (size_t)bh*HEADD*SEQLEN;

    // staging: lane-linear 16B chunks (global_load_lds writes base+lane*16;
    // per-lane LDS addr MUST be linear in t with stride 16 — rule 21 / m104)
    auto STAGE = [&](int b, int kt) {
        #pragma unroll
        for (int i = 0; i < 2; ++i) {
            int idx = t + 256*i;              // chunk 0..511
            int r = idx >> 3, ch = idx & 7;   // row, chunk-in-row
            int gch = ch ^ (r & 7);           // pre-swizzled source chunk
            __builtin_amdgcn_global_load_lds(
                (const GLOBAL_AS void*)(Kg + (size_t)(kt*64 + r)*HEADD + gch*8),
                (LDS_AS void*)((char*)&L[b][0] + idx*16), 16, 0, 0);
            __builtin_amdgcn_global_load_lds(
                (const GLOBAL_AS void*)(Vg + (size_t)r*SEQLEN + kt*64 + gch*8),
                (LDS_AS void*)((char*)&L[b][0] + 8192 + idx*16), 16, 0, 0);
        }
    };

    STAGE(0, 0);
    asm volatile("s_waitcnt vmcnt(0)" ::: "memory");
    __builtin_amdgcn_s_barrier();
    asm volatile("" ::: "memory");
    int buf = 0;
    const int NT = SEQLEN/64;
    for (int kt = 0; kt < NT; ++kt) {
        if (kt + 1 < NT) STAGE(buf^1, kt+1);
        const char* KL = (const char*)&L[buf][0];
        const char* VL = KL + 8192;
        // ---- QK^T swapped: sim[key][q] ----
        f32x16 sim0 = 0.0f, sim1 = 0.0f;
        #pragma unroll
        for (int dc = 0; dc < 4; ++dc) {
            short8 kf0 = *(const short8*)(KL + koffv[dc]);
            short8 kf1 = *(const short8*)(KL + koffv[dc] + 4096);
            sim0 = __builtin_amdgcn_mfma_f32_32x32x16_bf16(kf0, qf[dc], sim0, 0, 0, 0);
            sim1 = __builtin_amdgcn_mfma_f32_32x32x16_bf16(kf1, qf[dc], sim1, 0, 0, 0);
        }
        // ---- softmax, no max-tracking: P = exp2(sim') (q pre-scaled by log2e) ----
        unsigned int w0[8], w1[8];
        #pragma unroll
        for (int i = 0; i < 8; ++i) {
            float a0 = exp2f(sim0[2*i]), a1 = exp2f(sim0[2*i+1]);
            float b0 = exp2f(sim1[2*i]), b1 = exp2f(sim1[2*i+1]);
            lsum += (a0 + a1) + (b0 + b1);
            asm("v_cvt_pk_bf16_f32 %0, %1, %2" : "=v"(w0[i]) : "v"(a0), "v"(a1));
            asm("v_cvt_pk_bf16_f32 %0, %1, %2" : "=v"(w1[i]) : "v"(b0), "v"(b1));
        }
        // half-exchange: after swap, words [0..3] / [4..7] are PV B-fragments
        asm volatile("v_permlane32_swap_b32 %0, %1" : "+v"(w0[0]), "+v"(w0[2]));
        asm volatile("v_permlane32_swap_b32 %0, %1" : "+v"(w0[1]), "+v"(w0[3]));
        asm volatile("v_permlane32_swap_b32 %0, %1" : "+v"(w0[4]), "+v"(w0[6]));
        asm volatile("v_permlane32_swap_b32 %0, %1" : "+v"(w0[5]), "+v"(w0[7]));
        asm volatile("v_permlane32_swap_b32 %0, %1" : "+v"(w1[0]), "+v"(w1[2]));
        asm volatile("v_permlane32_swap_b32 %0, %1" : "+v"(w1[1]), "+v"(w1[3]));
        asm volatile("v_permlane32_swap_b32 %0, %1" : "+v"(w1[4]), "+v"(w1[6]));
        asm volatile("v_permlane32_swap_b32 %0, %1" : "+v"(w1[5]), "+v"(w1[7]));
        // ---- PV swapped: O^T[d][q] += V^T[d][k] P^T[k][q] ----
        #pragma unroll
        for (int ch = 0; ch < 2; ++ch) {          // key chunks 0,1 (sim0 keys)
            PW pw;
            pw.u[0] = w0[ch*4+0]; pw.u[1] = w0[ch*4+1];
            pw.u[2] = w0[ch*4+2]; pw.u[3] = w0[ch*4+3];
            short8 vf0 = *(const short8*)(VL + koffv[ch]);
            short8 vf1 = *(const short8*)(VL + koffv[ch] + 4096);
            oacc0 = __builtin_amdgcn_mfma_f32_32x32x16_bf16(vf0, pw.s, oacc0, 0, 0, 0);
            oacc1 = __builtin_amdgcn_mfma_f32_32x32x16_bf16(vf1, pw.s, oacc1, 0, 0, 0);
        }
        #pragma unroll
        for (int ch = 0; ch < 2; ++ch) {          // key chunks 2,3 (sim1 keys)
            PW pw;
            pw.u[0] = w1[ch*4+0]; pw.u[1] = w1[ch*4+1];
            pw.u[2] = w1[ch*4+2]; pw.u[3] = w1[ch*4+3];
            short8 vf0 = *(const short8*)(VL + koffv[2+ch]);
            short8 vf1 = *(const short8*)(VL + koffv[2+ch] + 4096);
            oacc0 = __builtin_amdgcn_mfma_f32_32x32x16_bf16(vf0, pw.s, oacc0, 0, 0, 0);
            oacc1 = __builtin_amdgcn_mfma_f32_32x32x16_bf16(vf1, pw.s, oacc1, 0, 0, 0);
        }
        asm volatile("s_waitcnt vmcnt(0)" ::: "memory");
        __builtin_amdgcn_s_barrier();
        asm volatile("" ::: "memory");
        buf ^= 1;
    }
    // ---- epilogue ----
    lsum += __shfl_xor(lsum, 32);
    float osc = 1.0f / lsum;
    if (OUTMODE == 0) osc *= LOG2E;
    unsigned short* orow;
    if (OUTMODE == 0) {
        orow = outp + ((size_t)bh*SEQLEN + q0 + wq*32 + q)*HEADD;
    } else {
        int bb = bh >> 4, h = bh & 15;
        orow = outp + ((size_t)bb*SEQLEN + q0 + wq*32 + q)*HDIM + h*HEADD;
    }
    const int dtab[8] = {0,2,8,10,16,18,24,26};
    #pragma unroll
    for (int i = 0; i < 8; ++i) {
        int d = dtab[i] + 4*hi;
        float a0 = oacc0[2*i]*osc, a1 = oacc0[2*i+1]*osc;
        unsigned int wv;
        asm("v_cvt_pk_bf16_f32 %0, %1, %2" : "=v"(wv) : "v"(a0), "v"(a1));
        *(unsigned int*)(orow + d) = wv;
    }
    #pragma unroll
    for (int i = 0; i < 8; ++i) {
        int d = 32 + dtab[i] + 4*hi;
        float a0 = oacc1[2*i]*osc, a1 = oacc1[2*i+1]*osc;
        unsigned int wv;
        asm("v_cvt_pk_bf16_f32 %0, %1, %2" : "=v"(wv) : "v"(a0), "v"(a1));
        *(unsigned int*)(orow + d) = wv;
    }
}

extern "C" void kernel_launch(void* const* d_in, const int* in_sizes, int n_in,
                              void* d_out, int out_size, void* d_ws, size_t ws_size,
                              hipStream_t stream) {
    const float* hs = (const float*)d_in[0];
    const float* Wq = (const float*)d_in[1];
    const float* bq = (const float*)d_in[2];
    const float* Wk = (const float*)d_in[3];
    const float* bk = (const float*)d_in[4];
    const float* Wv = (const float*)d_in[5];
    const float* bv = (const float*)d_in[6];
    const float* Wo = (const float*)d_in[7];
    const float* bo = (const float*)d_in[8];
    const float* lw = (const float*)d_in[9];
    const float* lb = (const float*)d_in[10];
    unsigned short* ws16 = (unsigned short*)d_ws;
    const size_t NE = (size_t)NROWS * HDIM;
    const size_t WE = (size_t)HDIM * HDIM;
    unsigned short* xn  = ws16;
    unsigned short* Wtq = xn + NE;
    unsigned short* Wtk = Wtq + WE;
    unsigned short* Wtv = Wtk + WE;
    unsigned short* Wto = Wtv + WE;
    unsigned short* qb  = Wto + WE;
    unsigned short* kb  = qb + NE;
    unsigned short* vt  = kb + NE;
    unsigned short* s1  = vt + NE;
    unsigned short* s2  = s1 + NE;

    ln_kernel<<<NROWS, 256, 0, stream>>>(hs, lw, lb, xn);
    dim3 wg(HDIM/64, HDIM/64);
    wconv_kernel<<<wg, 256, 0, stream>>>(Wq, Wtq);
    wconv_kernel<<<wg, 256, 0, stream>>>(Wk, Wtk);
    wconv_kernel<<<wg, 256, 0, stream>>>(Wv, Wtv);
    wconv_kernel<<<wg, 256, 0, stream>>>(Wo, Wto);
    dim3 gg(NROWS/128, HDIM/128);
    // q pre-scaled by log2e (exp2-domain softmax); k unit-normalized
    gemm_mfma_kernel<0><<<gg, 256, 0, stream>>>(xn, Wtq, bq, nullptr, qb, LOG2E);
    gemm_mfma_kernel<0><<<gg, 256, 0, stream>>>(xn, Wtk, bk, nullptr, kb, 1.0f);
    gemm_mfma_kernel<1><<<gg, 256, 0, stream>>>(xn, Wtv, bv, nullptr, vt, 1.0f);
    dim3 ag(SEQLEN/128, NBH);
    attn2_kernel<0><<<ag, 256, 0, stream>>>(qb, kb, vt, s1);
    attn2_kernel<1><<<ag, 256, 0, stream>>>(s1, kb, vt, s2);
    gemm_mfma_kernel<2><<<gg, 256, 0, stream>>>(s2, Wto, bo, hs, (void*)d_out, 1.0f);
}